// Round 6
// baseline (290.492 us; speedup 1.0000x reference)
//
#include <hip/hip_runtime.h>
#include <math.h>

// MultiHeadModulator: single-query complex multi-head attention over L=65536
// past positions, dim=256 (d2=512 real), H=8 heads.
//
// Algebraic reduction (k_proj/v_proj never materialized):
//   scores[l,h] = sum_i z[l,i]*wk[h,i] + ck[h] + relq[idx(l),h]
//   S_un[h,i]   = sum_l exp(scores[l,h]) * z[l,i]   (no max-sub: scores ~N(0,0.5))
//   s[h]        = sum_l exp(scores[l,h])
//   out_real[j] = sum_i Wv[j,i]*S_un[h(j),i]/s[h(j)] + bv[j]
//   out[j']     = sum_j Wo[j',j]*out_real[j] + bo[j']

static constexpr float SCALE = 0.17677669529663687f; // 1/sqrt(32)

__device__ __forceinline__ float wave_sum(float v) {
#pragma unroll
  for (int off = 32; off > 0; off >>= 1) v += __shfl_xor(v, off, 64);
  return v;
}

// y[j] = bias[j] + sum_i x[i]*M[j*512+i], 512 rows, one wave per row. grid=128
__global__ __launch_bounds__(256) void k_matvec512(
    const float* __restrict__ M, const float* __restrict__ x,
    const float* __restrict__ bias, float* __restrict__ y) {
  const int wave = threadIdx.x >> 6, lane = threadIdx.x & 63;
  const int j = blockIdx.x * 4 + wave;
  const float* Mr = M + (size_t)j * 512 + lane * 8;
  const float4 m0 = *(const float4*)Mr;
  const float4 m1 = *(const float4*)(Mr + 4);
  const float4 x0 = *(const float4*)(x + lane * 8);
  const float4 x1 = *(const float4*)(x + lane * 8 + 4);
  float acc = m0.x * x0.x + m0.y * x0.y + m0.z * x0.z + m0.w * x0.w +
              m1.x * x1.x + m1.y * x1.y + m1.z * x1.z + m1.w * x1.w;
  acc = wave_sum(acc);
  if (lane == 0) y[j] = acc + bias[j];
}

// Front-end: each block recomputes the 64-entry q_proj slice of its head h,
// then blocks 0..7 emit wk[h,:], ck[h], zero S_un[h,:]; blocks 8..15 emit
// relq[:,h]. grid=16.
__global__ __launch_bounds__(256) void k_front(
    const float* __restrict__ Wq, const float* __restrict__ bq,
    const float* __restrict__ zc, const float* __restrict__ Wk,
    const float* __restrict__ bk, const float* __restrict__ rb,
    float* __restrict__ wk, float* __restrict__ ck, float* __restrict__ relq,
    float* __restrict__ S_un) {
  __shared__ float ql[64];
  const int b = blockIdx.x;
  const int h = b & 7;
  const int wave = threadIdx.x >> 6, lane = threadIdx.x & 63;
  const float4 x0 = *(const float4*)(zc + lane * 8);
  const float4 x1 = *(const float4*)(zc + lane * 8 + 4);
  for (int rr = 0; rr < 16; ++rr) {
    const int j = h * 64 + wave * 16 + rr;
    const float* Mr = Wq + (size_t)j * 512 + lane * 8;
    const float4 m0 = *(const float4*)Mr;
    const float4 m1 = *(const float4*)(Mr + 4);
    float acc = m0.x * x0.x + m0.y * x0.y + m0.z * x0.z + m0.w * x0.w +
                m1.x * x1.x + m1.y * x1.y + m1.z * x1.z + m1.w * x1.w;
    acc = wave_sum(acc);
    if (lane == 0) ql[wave * 16 + rr] = acc + bq[j];
  }
  __syncthreads();
  if (b < 8) {
    if (wave == 0) {
      float acc = ql[lane] * bk[h * 64 + lane];
      acc = wave_sum(acc);
      if (lane == 0) ck[h] = acc * SCALE;
    }
    for (int i = threadIdx.x; i < 512; i += 256) {
      float acc = 0.f;
#pragma unroll
      for (int k = 0; k < 64; ++k)
        acc += ql[k] * Wk[(size_t)(h * 64 + k) * 512 + i];
      wk[h * 512 + i] = acc * SCALE;
      S_un[h * 512 + i] = 0.f;
    }
  } else {
    const int t = threadIdx.x;
    if (t < 129) {
      float acc = 0.f;
#pragma unroll
      for (int k = 0; k < 64; ++k)
        acc += ql[k] * rb[(size_t)t * 512 + h * 64 + k];
      relq[t * 8 + h] = acc * SCALE;
    }
  }
}

// Fused single pass: scores + exp + weighted z accumulation.
// 128 rows/block (32/wave); 4-row software pipeline, 4-row-ahead prefetch,
// pure pointer-walk addressing (no clamps on the address path).
// Requires L % 128 == 0 (holds: L=65536); grid = L/128.
__global__ __launch_bounds__(256, 2) void k_attn(
    const float* __restrict__ zp, const float* __restrict__ wk,
    const float* __restrict__ ck, const float* __restrict__ relq,
    const int* __restrict__ curr_pos, int L, float* __restrict__ Sp,
    float* __restrict__ sp) {
  __shared__ float relql[1032];
  __shared__ float Sl[4096];
  __shared__ float sl[4][8];
  const int tid = threadIdx.x;
  const int wave = tid >> 6, lane = tid & 63;
  for (int t = tid; t < 1032; t += 256) relql[t] = relq[t];

  float wkr[8][8];
#pragma unroll
  for (int h = 0; h < 8; ++h) {
    const float4 a = *(const float4*)(wk + h * 512 + lane * 8);
    const float4 b = *(const float4*)(wk + h * 512 + lane * 8 + 4);
    wkr[h][0] = a.x; wkr[h][1] = a.y; wkr[h][2] = a.z; wkr[h][3] = a.w;
    wkr[h][4] = b.x; wkr[h][5] = b.y; wkr[h][6] = b.z; wkr[h][7] = b.w;
  }
  // fold-reduce leaves lane holding head myh = bitrev3(lane&7)
  const int myh = ((lane & 1) << 2) | (lane & 2) | ((lane >> 2) & 1);
  const float ck_my = ck[myh];
  const int cp = curr_pos[0];
  __syncthreads();

  float S[8][8];
#pragma unroll
  for (int h = 0; h < 8; ++h)
#pragma unroll
    for (int k = 0; k < 8; ++k) S[h][k] = 0.f;
  float s_loc = 0.f;

  const int l0 = blockIdx.x * 128 + wave * 32;

  auto process = [&](const float4& z0, const float4& z1, int l) {
    const float zz[8] = {z0.x, z0.y, z0.z, z0.w, z1.x, z1.y, z1.z, z1.w};
    float acc[8];
#pragma unroll
    for (int h = 0; h < 8; ++h) {
      float a = 0.f;
#pragma unroll
      for (int k = 0; k < 8; ++k) a += zz[k] * wkr[h][k];
      acc[h] = a;
    }
    // fold-reduce: 8 values across 64 lanes in 10 shuffles
    const bool lo1 = (lane & 1) == 0;
    float b0 = (lo1 ? acc[0] : acc[4]) + __shfl_xor(lo1 ? acc[4] : acc[0], 1, 64);
    float b1 = (lo1 ? acc[1] : acc[5]) + __shfl_xor(lo1 ? acc[5] : acc[1], 1, 64);
    float b2 = (lo1 ? acc[2] : acc[6]) + __shfl_xor(lo1 ? acc[6] : acc[2], 1, 64);
    float b3 = (lo1 ? acc[3] : acc[7]) + __shfl_xor(lo1 ? acc[7] : acc[3], 1, 64);
    const bool lo2 = (lane & 2) == 0;
    float c0 = (lo2 ? b0 : b2) + __shfl_xor(lo2 ? b2 : b0, 2, 64);
    float c1 = (lo2 ? b1 : b3) + __shfl_xor(lo2 ? b3 : b1, 2, 64);
    const bool lo3 = (lane & 4) == 0;
    float d = (lo3 ? c0 : c1) + __shfl_xor(lo3 ? c1 : c0, 4, 64);
    d += __shfl_xor(d, 8, 64);
    d += __shfl_xor(d, 16, 64);
    d += __shfl_xor(d, 32, 64);

    int dd = cp - L + l + 64;
    dd = dd < 0 ? 0 : (dd > 128 ? 128 : dd);
    const float w = __expf(d + ck_my + relql[dd * 8 + myh]);
    s_loc += w;
#pragma unroll
    for (int h = 0; h < 8; ++h) {
      const int src = ((h & 1) << 2) | (h & 2) | ((h >> 2) & 1);
      const float wh = __shfl(w, src, 64);
#pragma unroll
      for (int k = 0; k < 8; ++k) S[h][k] += wh * zz[k];
    }
  };

  const float* zr = zp + (size_t)l0 * 512 + lane * 8;
  // preload rows 0..3 into the pipeline registers
  float4 P0 = *(const float4*)zr;
  float4 P1 = *(const float4*)(zr + 4);
  float4 P2 = *(const float4*)(zr + 512);
  float4 P3 = *(const float4*)(zr + 516);
  float4 P4 = *(const float4*)(zr + 1024);
  float4 P5 = *(const float4*)(zr + 1028);
  float4 P6 = *(const float4*)(zr + 1536);
  float4 P7 = *(const float4*)(zr + 1540);
  // two walking prefetch pointers (rows r+4 and r+6)
  const float* fa = zr + 2048;
  const float* fb = zr + 3072;

  for (int it = 0; it < 7; ++it) {
    const float4 N0 = *(const float4*)fa;
    const float4 N1 = *(const float4*)(fa + 4);
    const float4 N2 = *(const float4*)(fa + 512);
    const float4 N3 = *(const float4*)(fa + 516);
    const float4 N4 = *(const float4*)fb;
    const float4 N5 = *(const float4*)(fb + 4);
    const float4 N6 = *(const float4*)(fb + 512);
    const float4 N7 = *(const float4*)(fb + 516);
    const int l = l0 + it * 4;
    process(P0, P1, l);
    process(P2, P3, l + 1);
    process(P4, P5, l + 2);
    process(P6, P7, l + 3);
    P0 = N0; P1 = N1; P2 = N2; P3 = N3;
    P4 = N4; P5 = N5; P6 = N6; P7 = N7;
    fa += 2048; fb += 2048;
  }
  // tail: rows 28..31 (no prefetch)
  process(P0, P1, l0 + 28);
  process(P2, P3, l0 + 29);
  process(P4, P5, l0 + 30);
  process(P6, P7, l0 + 31);

  if (lane < 8) sl[wave][myh] = s_loc;
  // merge the 4 waves' register tiles into LDS
  for (int wv = 0; wv < 4; ++wv) {
    if (wave == wv) {
#pragma unroll
      for (int h = 0; h < 8; ++h)
#pragma unroll
        for (int k = 0; k < 8; ++k) {
          const int idx = h * 512 + lane * 8 + k;
          if (wv == 0) Sl[idx] = S[h][k];
          else Sl[idx] += S[h][k];
        }
    }
    __syncthreads();
  }
  for (int t = tid; t < 4096; t += 256)
    Sp[(size_t)blockIdx.x * 4096 + t] = Sl[t];
  if (tid < 8)
    sp[blockIdx.x * 8 + tid] = sl[0][tid] + sl[1][tid] + sl[2][tid] + sl[3][tid];
}

// combine block partials. blocks 0..255: S_un (atomic, pre-zeroed by k_front);
// block 256: s. grid=257
__global__ __launch_bounds__(256) void k_comb2(
    const float* __restrict__ Sp, const float* __restrict__ spv, int nb,
    float* __restrict__ S_un, float* __restrict__ s) {
  if (blockIdx.x < 256) {
    const int T = blockIdx.x * 256 + threadIdx.x;
    const int col = T & 4095;
    const int g = T >> 12;  // 0..15
    const int chunk = (nb + 15) >> 4;
    const int r0 = g * chunk;
    const int r1 = min(r0 + chunk, nb);
    float a[8];
#pragma unroll
    for (int u = 0; u < 8; ++u) a[u] = 0.f;
    int b = r0;
    for (; b + 8 <= r1; b += 8) {
#pragma unroll
      for (int u = 0; u < 8; ++u) a[u] += Sp[(size_t)(b + u) * 4096 + col];
    }
    for (; b < r1; ++b) a[0] += Sp[(size_t)b * 4096 + col];
    const float t = ((a[0] + a[1]) + (a[2] + a[3])) +
                    ((a[4] + a[5]) + (a[6] + a[7]));
    atomicAdd(&S_un[col], t);
  } else {
    __shared__ float red[256];
    float a = 0.f;
    for (int b2 = threadIdx.x >> 3; b2 < nb; b2 += 32)
      a += spv[b2 * 8 + (threadIdx.x & 7)];
    red[threadIdx.x] = a;
    __syncthreads();
    if (threadIdx.x < 8) {
      float x = 0.f;
      for (int c = 0; c < 32; ++c) x += red[c * 8 + threadIdx.x];
      s[threadIdx.x] = x;
    }
  }
}

// out_real[j] = bv[j] + (sum_i Wv[j,i]*S_un[h(j),i]) / s[h(j)]. grid=128
__global__ __launch_bounds__(256) void k_outreal(
    const float* __restrict__ Wv, const float* __restrict__ S_un,
    const float* __restrict__ s, const float* __restrict__ bv,
    float* __restrict__ out_real) {
  const int wave = threadIdx.x >> 6, lane = threadIdx.x & 63;
  const int j = blockIdx.x * 4 + wave;
  const int h = j >> 6;
  const float* Mr = Wv + (size_t)j * 512 + lane * 8;
  const float* xr = S_un + h * 512 + lane * 8;
  const float4 m0 = *(const float4*)Mr;
  const float4 m1 = *(const float4*)(Mr + 4);
  const float4 x0 = *(const float4*)xr;
  const float4 x1 = *(const float4*)(xr + 4);
  float acc = m0.x * x0.x + m0.y * x0.y + m0.z * x0.z + m0.w * x0.w +
              m1.x * x1.x + m1.y * x1.y + m1.z * x1.z + m1.w * x1.w;
  acc = wave_sum(acc);
  if (lane == 0) out_real[j] = acc / s[h] + bv[j];
}

extern "C" void kernel_launch(void* const* d_in, const int* in_sizes, int n_in,
                              void* d_out, int out_size, void* d_ws,
                              size_t ws_size, hipStream_t stream) {
  const int* curr_pos = (const int*)d_in[0];
  const float* z_curr = (const float*)d_in[1];
  const float* z_past = (const float*)d_in[2];
  const float* Wq = (const float*)d_in[3];
  const float* bq = (const float*)d_in[4];
  const float* Wk = (const float*)d_in[5];
  const float* bk = (const float*)d_in[6];
  const float* Wv = (const float*)d_in[7];
  const float* bv = (const float*)d_in[8];
  const float* Wo = (const float*)d_in[9];
  const float* bo = (const float*)d_in[10];
  const float* rb = (const float*)d_in[11];
  float* out = (float*)d_out;

  const int L = in_sizes[2] / 512;
  const int nb = (L + 127) / 128;  // attn blocks (128 rows each)

  float* ws = (float*)d_ws;
  size_t o = 0;
  float* wk = ws + o;       o += 8 * 512;
  float* ck = ws + o;       o += 16;
  float* relq = ws + o;     o += 1040;
  float* s = ws + o;        o += 8;
  float* sp = ws + o;       o += (size_t)nb * 8;
  float* S_un = ws + o;     o += 4096;
  float* out_real = ws + o; o += 512;
  float* Sp = ws + o;       o += (size_t)nb * 4096;
  (void)ws_size; (void)n_in; (void)out_size;

  k_front<<<16, 256, 0, stream>>>(Wq, bq, z_curr, Wk, bk, rb, wk, ck, relq,
                                  S_un);
  k_attn<<<nb, 256, 0, stream>>>(z_past, wk, ck, relq, curr_pos, L, Sp, sp);
  k_comb2<<<257, 256, 0, stream>>>(Sp, sp, nb, S_un, s);
  k_outreal<<<128, 256, 0, stream>>>(Wv, S_un, s, bv, out_real);
  k_matvec512<<<128, 256, 0, stream>>>(Wo, out_real, bo, out);
}

// Round 7
// 247.664 us; speedup vs baseline: 1.1729x; 1.1729x over previous
//
#include <hip/hip_runtime.h>
#include <math.h>

// MultiHeadModulator: single-query complex multi-head attention over L=65536
// past positions, dim=256 (d2=512 real), H=8 heads.
//
//   scores[l,h] = sum_i z[l,i]*wk[h,i] + ck[h] + relq[idx(l),h]
//   S_un[h,i]   = sum_l exp(scores[l,h]) * z[l,i]   (no max-sub: scores ~N(0,0.5))
//   s[h]        = sum_l exp(scores[l,h])
//   out_real[j] = sum_i Wv[j,i]*S_un[h(j),i]/s[h(j)] + bv[j]
//   out[j']     = sum_j Wo[j',j]*out_real[j] + bo[j']

static constexpr float SCALE = 0.17677669529663687f; // 1/sqrt(32)

__device__ __forceinline__ float wave_sum(float v) {
#pragma unroll
  for (int off = 32; off > 0; off >>= 1) v += __shfl_xor(v, off, 64);
  return v;
}

// y[j] = bias[j] + sum_i x[i]*M[j*512+i], 512 rows, one wave per row. grid=128
__global__ __launch_bounds__(256) void k_matvec512(
    const float* __restrict__ M, const float* __restrict__ x,
    const float* __restrict__ bias, float* __restrict__ y) {
  const int wave = threadIdx.x >> 6, lane = threadIdx.x & 63;
  const int j = blockIdx.x * 4 + wave;
  const float* Mr = M + (size_t)j * 512 + lane * 8;
  const float4 m0 = *(const float4*)Mr;
  const float4 m1 = *(const float4*)(Mr + 4);
  const float4 x0 = *(const float4*)(x + lane * 8);
  const float4 x1 = *(const float4*)(x + lane * 8 + 4);
  float acc = m0.x * x0.x + m0.y * x0.y + m0.z * x0.z + m0.w * x0.w +
              m1.x * x1.x + m1.y * x1.y + m1.z * x1.z + m1.w * x1.w;
  acc = wave_sum(acc);
  if (lane == 0) y[j] = acc + bias[j];
}

// wkpart[b,i] = sum_{j in [32b,32b+32)} qp[j]*Wk[j,i].  grid=16
__global__ __launch_bounds__(256) void k_wkpart(
    const float* __restrict__ Wk, const float* __restrict__ qp,
    float* __restrict__ wkpart) {
  __shared__ float ql[32];
  const int b = blockIdx.x;
  if (threadIdx.x < 32) ql[threadIdx.x] = qp[b * 32 + threadIdx.x];
  __syncthreads();
  for (int i = threadIdx.x; i < 512; i += 256) {
    float acc = 0.f;
#pragma unroll
    for (int k = 0; k < 32; ++k)
      acc += ql[k] * Wk[(size_t)(b * 32 + k) * 512 + i];
    wkpart[b * 512 + i] = acc;
  }
}

// blocks 0..7: wk; block 8: ck; blocks 9..13: relq; block 14: zero S_un. grid=15
__global__ __launch_bounds__(256) void k_misc(
    const float* __restrict__ qp, const float* __restrict__ bk,
    const float* __restrict__ rb, const float* __restrict__ wkpart,
    float* __restrict__ wk, float* __restrict__ ck, float* __restrict__ relq,
    float* __restrict__ S_un) {
  const int b = blockIdx.x;
  if (b < 8) {
    for (int i = threadIdx.x; i < 512; i += 256)
      wk[b * 512 + i] =
          (wkpart[(2 * b) * 512 + i] + wkpart[(2 * b + 1) * 512 + i]) * SCALE;
  } else if (b == 8) {
    if (threadIdx.x < 8) {
      const int h = threadIdx.x;
      float acc = 0.f;
      for (int k = 0; k < 64; ++k) acc += qp[h * 64 + k] * bk[h * 64 + k];
      ck[h] = acc * SCALE;
    }
  } else if (b < 14) {
    const int t = (b - 9) * 256 + threadIdx.x;
    if (t < 129 * 8) {
      const int idx = t >> 3, h = t & 7;
      float acc = 0.f;
      for (int k = 0; k < 64; ++k)
        acc += qp[h * 64 + k] * rb[(size_t)idx * 512 + h * 64 + k];
      relq[t * 8 + h] = acc * SCALE;
    }
  } else {
    for (int t = threadIdx.x; t < 4096; t += 256) S_un[t] = 0.f;
  }
}

// Fused single pass: scores + exp + weighted z accumulation.
// 128 rows/block (32/wave); 4-row batched fold-reduction (chain depth 6 per
// 4 rows, 8 shuffles/row, 1 exp per lane per 4 rows). Requires L%128==0.
__global__ __launch_bounds__(256, 2) void k_attn(
    const float* __restrict__ zp, const float* __restrict__ wk,
    const float* __restrict__ ck, const float* __restrict__ relq,
    const int* __restrict__ curr_pos, int L, float* __restrict__ Sp,
    float* __restrict__ sp) {
  __shared__ float relql[1032];
  __shared__ float Sl[4096];
  __shared__ float sl[4][32];
  const int tid = threadIdx.x;
  const int wave = tid >> 6, lane = tid & 63;
  for (int t = tid; t < 1032; t += 256) relql[t] = relq[t];

  float wkr[8][8];
#pragma unroll
  for (int h = 0; h < 8; ++h) {
    const float4 a = *(const float4*)(wk + h * 512 + lane * 8);
    const float4 b = *(const float4*)(wk + h * 512 + lane * 8 + 4);
    wkr[h][0] = a.x; wkr[h][1] = a.y; wkr[h][2] = a.z; wkr[h][3] = a.w;
    wkr[h][4] = b.x; wkr[h][5] = b.y; wkr[h][6] = b.z; wkr[h][7] = b.w;
  }
  // after the LSB-first fold, lane r*8+h (and +32 dup) holds score(row r, head h)
  const int myh = lane & 7;
  const int myr = (lane >> 3) & 3;
  const float ck_my = ck[myh];
  const int cp = curr_pos[0];
  __syncthreads();

  float S[8][8];
#pragma unroll
  for (int h = 0; h < 8; ++h)
#pragma unroll
    for (int k = 0; k < 8; ++k) S[h][k] = 0.f;
  float s_loc = 0.f;

  const int l0 = blockIdx.x * 128 + wave * 32;
  const float* zr = zp + (size_t)l0 * 512 + lane * 8;
  float4 P0 = *(const float4*)zr;
  float4 P1 = *(const float4*)(zr + 4);
  float4 P2 = *(const float4*)(zr + 512);
  float4 P3 = *(const float4*)(zr + 516);
  float4 P4 = *(const float4*)(zr + 1024);
  float4 P5 = *(const float4*)(zr + 1028);
  float4 P6 = *(const float4*)(zr + 1536);
  float4 P7 = *(const float4*)(zr + 1540);
  const float* f = zr + 2048;

  auto quad = [&](int itbase) {
    const float zz[4][8] = {
        {P0.x, P0.y, P0.z, P0.w, P1.x, P1.y, P1.z, P1.w},
        {P2.x, P2.y, P2.z, P2.w, P3.x, P3.y, P3.z, P3.w},
        {P4.x, P4.y, P4.z, P4.w, P5.x, P5.y, P5.z, P5.w},
        {P6.x, P6.y, P6.z, P6.w, P7.x, P7.y, P7.z, P7.w}};
    float a32[32];
#pragma unroll
    for (int r = 0; r < 4; ++r)
#pragma unroll
      for (int h = 0; h < 8; ++h) {
        float a = 0.f;
#pragma unroll
        for (int k = 0; k < 8; ++k) a += zz[r][k] * wkr[h][k];
        a32[r * 8 + h] = a;
      }
    // batched fold: 32 scalars -> 1 per lane across 6 xor stages (LSB first)
    float a16[16];
    {
      const bool lo = (lane & 1) == 0;
#pragma unroll
      for (int i = 0; i < 16; ++i)
        a16[i] = (lo ? a32[2 * i] : a32[2 * i + 1]) +
                 __shfl_xor(lo ? a32[2 * i + 1] : a32[2 * i], 1, 64);
    }
    float a8v[8];
    {
      const bool lo = (lane & 2) == 0;
#pragma unroll
      for (int i = 0; i < 8; ++i)
        a8v[i] = (lo ? a16[2 * i] : a16[2 * i + 1]) +
                 __shfl_xor(lo ? a16[2 * i + 1] : a16[2 * i], 2, 64);
    }
    float a4v[4];
    {
      const bool lo = (lane & 4) == 0;
#pragma unroll
      for (int i = 0; i < 4; ++i)
        a4v[i] = (lo ? a8v[2 * i] : a8v[2 * i + 1]) +
                 __shfl_xor(lo ? a8v[2 * i + 1] : a8v[2 * i], 4, 64);
    }
    float a2v[2];
    {
      const bool lo = (lane & 8) == 0;
#pragma unroll
      for (int i = 0; i < 2; ++i)
        a2v[i] = (lo ? a4v[2 * i] : a4v[2 * i + 1]) +
                 __shfl_xor(lo ? a4v[2 * i + 1] : a4v[2 * i], 8, 64);
    }
    float a1v;
    {
      const bool lo = (lane & 16) == 0;
      a1v = (lo ? a2v[0] : a2v[1]) +
            __shfl_xor(lo ? a2v[1] : a2v[0], 16, 64);
    }
    const float sc = a1v + __shfl_xor(a1v, 32, 64);

    const int l = l0 + itbase + myr;
    int dd = cp - L + l + 64;
    dd = dd < 0 ? 0 : (dd > 128 ? 128 : dd);
    const float w = __expf(sc + ck_my + relql[dd * 8 + myh]);
    s_loc += w;
#pragma unroll
    for (int r = 0; r < 4; ++r)
#pragma unroll
      for (int h = 0; h < 8; ++h) {
        const float wh = __shfl(w, r * 8 + h, 64);
#pragma unroll
        for (int k = 0; k < 8; ++k) S[h][k] += wh * zz[r][k];
      }
  };

  for (int it = 0; it < 7; ++it) {
    const float4 N0 = *(const float4*)f;
    const float4 N1 = *(const float4*)(f + 4);
    const float4 N2 = *(const float4*)(f + 512);
    const float4 N3 = *(const float4*)(f + 516);
    const float4 N4 = *(const float4*)(f + 1024);
    const float4 N5 = *(const float4*)(f + 1028);
    const float4 N6 = *(const float4*)(f + 1536);
    const float4 N7 = *(const float4*)(f + 1540);
    quad(it * 4);
    P0 = N0; P1 = N1; P2 = N2; P3 = N3;
    P4 = N4; P5 = N5; P6 = N6; P7 = N7;
    f += 2048;
  }
  quad(28);  // tail rows 28..31, no prefetch

  if (lane < 32) sl[wave][lane] = s_loc;
  // merge the 4 waves' register tiles into LDS
  for (int wv = 0; wv < 4; ++wv) {
    if (wave == wv) {
#pragma unroll
      for (int h = 0; h < 8; ++h)
#pragma unroll
        for (int k = 0; k < 8; ++k) {
          const int idx = h * 512 + lane * 8 + k;
          if (wv == 0) Sl[idx] = S[h][k];
          else Sl[idx] += S[h][k];
        }
    }
    __syncthreads();
  }
  for (int t = tid; t < 4096; t += 256)
    Sp[(size_t)blockIdx.x * 4096 + t] = Sl[t];
  if (tid < 8) {
    float x = 0.f;
#pragma unroll
    for (int wv = 0; wv < 4; ++wv)
#pragma unroll
      for (int rr = 0; rr < 4; ++rr) x += sl[wv][rr * 8 + tid];
    sp[blockIdx.x * 8 + tid] = x;
  }
}

// combine block partials. blocks 0..255: S_un (atomic, pre-zeroed by k_misc);
// block 256: s. grid=257
__global__ __launch_bounds__(256) void k_comb2(
    const float* __restrict__ Sp, const float* __restrict__ spv, int nb,
    float* __restrict__ S_un, float* __restrict__ s) {
  if (blockIdx.x < 256) {
    const int T = blockIdx.x * 256 + threadIdx.x;
    const int col = T & 4095;
    const int g = T >> 12;  // 0..15
    const int chunk = (nb + 15) >> 4;
    const int r0 = g * chunk;
    const int r1 = min(r0 + chunk, nb);
    float a[8];
#pragma unroll
    for (int u = 0; u < 8; ++u) a[u] = 0.f;
    int b = r0;
    for (; b + 8 <= r1; b += 8) {
#pragma unroll
      for (int u = 0; u < 8; ++u) a[u] += Sp[(size_t)(b + u) * 4096 + col];
    }
    for (; b < r1; ++b) a[0] += Sp[(size_t)b * 4096 + col];
    const float t = ((a[0] + a[1]) + (a[2] + a[3])) +
                    ((a[4] + a[5]) + (a[6] + a[7]));
    atomicAdd(&S_un[col], t);
  } else {
    __shared__ float red[256];
    float a = 0.f;
    for (int b2 = threadIdx.x >> 3; b2 < nb; b2 += 32)
      a += spv[b2 * 8 + (threadIdx.x & 7)];
    red[threadIdx.x] = a;
    __syncthreads();
    if (threadIdx.x < 8) {
      float x = 0.f;
      for (int c = 0; c < 32; ++c) x += red[c * 8 + threadIdx.x];
      s[threadIdx.x] = x;
    }
  }
}

// out_real[j] = bv[j] + (sum_i Wv[j,i]*S_un[h(j),i]) / s[h(j)]. grid=128
__global__ __launch_bounds__(256) void k_outreal(
    const float* __restrict__ Wv, const float* __restrict__ S_un,
    const float* __restrict__ s, const float* __restrict__ bv,
    float* __restrict__ out_real) {
  const int wave = threadIdx.x >> 6, lane = threadIdx.x & 63;
  const int j = blockIdx.x * 4 + wave;
  const int h = j >> 6;
  const float* Mr = Wv + (size_t)j * 512 + lane * 8;
  const float* xr = S_un + h * 512 + lane * 8;
  const float4 m0 = *(const float4*)Mr;
  const float4 m1 = *(const float4*)(Mr + 4);
  const float4 x0 = *(const float4*)xr;
  const float4 x1 = *(const float4*)(xr + 4);
  float acc = m0.x * x0.x + m0.y * x0.y + m0.z * x0.z + m0.w * x0.w +
              m1.x * x1.x + m1.y * x1.y + m1.z * x1.z + m1.w * x1.w;
  acc = wave_sum(acc);
  if (lane == 0) out_real[j] = acc / s[h] + bv[j];
}

extern "C" void kernel_launch(void* const* d_in, const int* in_sizes, int n_in,
                              void* d_out, int out_size, void* d_ws,
                              size_t ws_size, hipStream_t stream) {
  const int* curr_pos = (const int*)d_in[0];
  const float* z_curr = (const float*)d_in[1];
  const float* z_past = (const float*)d_in[2];
  const float* Wq = (const float*)d_in[3];
  const float* bq = (const float*)d_in[4];
  const float* Wk = (const float*)d_in[5];
  const float* bk = (const float*)d_in[6];
  const float* Wv = (const float*)d_in[7];
  const float* bv = (const float*)d_in[8];
  const float* Wo = (const float*)d_in[9];
  const float* bo = (const float*)d_in[10];
  const float* rb = (const float*)d_in[11];
  float* out = (float*)d_out;

  const int L = in_sizes[2] / 512;
  const int nb = (L + 127) / 128;  // attn blocks (128 rows each)

  float* ws = (float*)d_ws;
  size_t o = 0;
  float* qp = ws + o;       o += 512;
  float* wkpart = ws + o;   o += 16 * 512;
  float* wk = ws + o;       o += 8 * 512;
  float* ck = ws + o;       o += 16;
  float* relq = ws + o;     o += 1040;
  float* s = ws + o;        o += 8;
  float* sp = ws + o;       o += (size_t)nb * 8;
  float* S_un = ws + o;     o += 4096;
  float* out_real = ws + o; o += 512;
  float* Sp = ws + o;       o += (size_t)nb * 4096;
  (void)ws_size; (void)n_in; (void)out_size;

  k_matvec512<<<128, 256, 0, stream>>>(Wq, z_curr, bq, qp);
  k_wkpart<<<16, 256, 0, stream>>>(Wk, qp, wkpart);
  k_misc<<<15, 256, 0, stream>>>(qp, bk, rb, wkpart, wk, ck, relq, S_un);
  k_attn<<<nb, 256, 0, stream>>>(z_past, wk, ck, relq, curr_pos, L, Sp, sp);
  k_comb2<<<257, 256, 0, stream>>>(Sp, sp, nb, S_un, s);
  k_outreal<<<128, 256, 0, stream>>>(Wv, S_un, s, bv, out_real);
  k_matvec512<<<128, 256, 0, stream>>>(Wo, out_real, bo, out);
}